// Round 8
// baseline (581.900 us; speedup 1.0000x reference)
//
#include <hip/hip_runtime.h>
#include <math.h>

#define HD    128
#define NQH   32
#define NKVH  8
#define GQA   4
#define PBLK  16      // paged cache block size
#define MAXNB 160     // max block-table entries cached in LDS
#define CHUNK 128     // tokens per staged chunk
#define RS    132     // padded LDS row stride in floats (128 + 4)

#define L2_10000 13.287712379549449f   // log2(10000)

typedef float f4 __attribute__((ext_vector_type(4)));

// token base pointer (K or V) for token t; t == T means "current" k/v
__device__ __forceinline__ const float* tok_base(
    const float* __restrict__ cache, const float* __restrict__ cur,
    const int* __restrict__ btrow, int t, int T, int b, int h)
{
    if (t == T) return cur + ((size_t)b * NKVH + h) * HD;
    int blk = btrow[t >> 4];
    return cache + (((size_t)blk * PBLK + (t & (PBLK - 1))) * NKVH + h) * HD;
}

// interleaved rope table: tab[t*128 + 2*f] = cos(t*invf[f]), [2*f+1] = sin
__global__ void rope_table_kernel(float* __restrict__ tab, int T) {
    int idx = blockIdx.x * blockDim.x + threadIdx.x;
    int total = (T + 1) * 64;
    if (idx >= total) return;
    int t = idx >> 6;
    int f = idx & 63;
    float invf = exp2f(-(float)f * (L2_10000 / 64.0f));
    float ss, cc;
    sincosf((float)t * invf, &ss, &cc);
    tab[(size_t)t * 128 + 2 * f]     = cc;
    tab[(size_t)t * 128 + 2 * f + 1] = ss;
}

// One block per (b,h). Per 128-token chunk: deep register prefetch (8 K + 8 V
// + 8 tab f4/lane issued back-to-back, spanning the whole compute phase) ->
// LDS stage -> in-LDS dot (4 thr/token, 2 shuffles) -> block softmax -> PV.
// Rounds 2-6 were pinned at ~170us (=32 iters x 5.3us) by 1-deep prefetch:
// ~2-6 lines in flight/wave -> ~3 TB/s latency-bound. This keeps ~16+
// lines/lane in flight continuously.
__global__ __launch_bounds__(512) void paged_attn_kernel(
    const float* __restrict__ q,
    const float* __restrict__ kcur,
    const float* __restrict__ vcur,
    const float* __restrict__ kc,
    const float* __restrict__ vc,
    const int* __restrict__ bt,
    const float* __restrict__ tab,
    float* __restrict__ out,
    int T, int nb, int useTable)
{
    const int b   = blockIdx.x >> 3;
    const int h   = blockIdx.x & 7;
    const int tid = threadIdx.x;
    const int hw  = tid >> 5;      // half-wave 0..15 (stage/PV: token owner)
    const int il  = tid & 31;      // lane in half-wave: dims [4il,4il+4)
    const int w   = tid >> 6;      // wave 0..7
    const int tt4 = tid >> 2;      // dot phase: token 0..127
    const int j4  = tid & 3;       // dot phase: quarter 0..3 (pairs [16j,16j+16))

    __shared__ float Kt[CHUNK * RS];          // 67.6 KB
    __shared__ float Vt[CHUNK * RS];          // 67.6 KB
    __shared__ float sc[CHUNK * 4];           // scores/p [t][g]
    __shared__ float qlo[4 * 64], qhi[4 * 64];
    __shared__ float redM[8][4], redL[8][4];
    __shared__ int   sbt[MAXNB];

    const int* btrow = bt + (size_t)b * nb;
    if (nb <= MAXNB) for (int i = tid; i < nb; i += 512) sbt[i] = btrow[i];

    if (tid < 256) {   // rope current q (4 heads), scale folded in
        const int g = tid >> 6, f = tid & 63;
        const float* qb = q + ((size_t)b * NQH + h * GQA + g) * HD;
        float xlo = qb[f], xhi = qb[64 + f];
        float cc, ss;
        if (useTable) {
            cc = tab[(size_t)T * 128 + 2 * f];
            ss = tab[(size_t)T * 128 + 2 * f + 1];
        } else {
            float invf = exp2f(-(float)f * (L2_10000 / 64.0f));
            sincosf((float)T * invf, &ss, &cc);
        }
        const float scale = 0.08838834764831845f;   // 128^-0.5
        qlo[g * 64 + f] = (xlo * cc - xhi * ss) * scale;
        qhi[g * 64 + f] = (xhi * cc + xlo * ss) * scale;
    }
    __syncthreads();
    if (nb <= MAXNB) btrow = sbt;

    const int total = T + 1;
    const int nc = (total + CHUNK - 1) / CHUNK;

    float Mr0 = -INFINITY, Mr1 = -INFINITY, Mr2 = -INFINITY, Mr3 = -INFINITY;
    float Lr0 = 0.f, Lr1 = 0.f, Lr2 = 0.f, Lr3 = 0.f;
    f4 o[4] = {};

    f4 kreg[8], vreg[8], treg[8];

    auto LOADKV = [&](int c) {
        const int clo = c * CHUNK;
#pragma unroll
        for (int it = 0; it < 8; ++it) {
            int t = clo + hw + 16 * it;
            if (t < total) {
                const float* kb = tok_base(kc, kcur, btrow, t, T, b, h);
                const float* vb = tok_base(vc, vcur, btrow, t, T, b, h);
                kreg[it] = *(const f4*)(kb + 4 * il);
                vreg[it] = *(const f4*)(vb + 4 * il);
            }
        }
    };
    auto LOADT = [&](int c) {
        if (!useTable) return;
        int tc = min(c * CHUNK + tt4, T);
        const float* tb = tab + (size_t)tc * 128 + j4 * 32;
#pragma unroll
        for (int i = 0; i < 8; ++i) treg[i] = *(const f4*)(tb + 4 * i);
    };
    auto WRITE = [&](int c) {
        const int clo = c * CHUNK;
#pragma unroll
        for (int it = 0; it < 8; ++it) {
            int tt = hw + 16 * it;
            if (clo + tt < total) {
                *(f4*)&Kt[tt * RS + 4 * il] = kreg[it];
                *(f4*)&Vt[tt * RS + 4 * il] = vreg[it];
            }
        }
    };

    LOADKV(0);
    LOADT(0);
    WRITE(0);
    __syncthreads();

    for (int c = 0; c < nc; ++c) {
        const int clo = c * CHUNK;
        const int cn  = min(CHUNK, total - clo);

        // issue next chunk's K/V loads: they stay in flight across the whole
        // compute phase below (T14 async-stage split)
        if (c + 1 < nc) LOADKV(c + 1);

        // ---- dot: 4 threads per token, all in-lane from LDS ----
        {
            float a0 = 0.f, a1 = 0.f, a2 = 0.f, a3 = 0.f;
            const int base = tt4 * RS + j4 * 16;
#pragma unroll
            for (int g4 = 0; g4 < 4; ++g4) {
                f4 klo = *(const f4*)&Kt[base + 4 * g4];
                f4 khi = *(const f4*)&Kt[base + 64 + 4 * g4];
                f4 cs0, cs1;
                if (useTable) {
                    cs0 = treg[2 * g4];
                    cs1 = treg[2 * g4 + 1];
                } else {
                    int f0 = j4 * 16 + g4 * 4;
                    float fb = (float)min(clo + tt4, T);
                    float ssx, ccx;
                    float i0 = exp2f(-(float)(f0    ) * (L2_10000 / 64.0f));
                    sincosf(fb * i0, &ssx, &ccx); cs0.x = ccx; cs0.y = ssx;
                    float i1 = exp2f(-(float)(f0 + 1) * (L2_10000 / 64.0f));
                    sincosf(fb * i1, &ssx, &ccx); cs0.z = ccx; cs0.w = ssx;
                    float i2 = exp2f(-(float)(f0 + 2) * (L2_10000 / 64.0f));
                    sincosf(fb * i2, &ssx, &ccx); cs1.x = ccx; cs1.y = ssx;
                    float i3 = exp2f(-(float)(f0 + 3) * (L2_10000 / 64.0f));
                    sincosf(fb * i3, &ssx, &ccx); cs1.z = ccx; cs1.w = ssx;
                }
                f4 krlo, krhi;
                krlo.x = klo.x * cs0.x - khi.x * cs0.y;  krhi.x = khi.x * cs0.x + klo.x * cs0.y;
                krlo.y = klo.y * cs0.z - khi.y * cs0.w;  krhi.y = khi.y * cs0.z + klo.y * cs0.w;
                krlo.z = klo.z * cs1.x - khi.z * cs1.y;  krhi.z = khi.z * cs1.x + klo.z * cs1.y;
                krlo.w = klo.w * cs1.z - khi.w * cs1.w;  krhi.w = khi.w * cs1.z + klo.w * cs1.w;

                const int qb0 = j4 * 16 + 4 * g4;
                f4 ql, qh;
                ql = *(const f4*)&qlo[qb0];        qh = *(const f4*)&qhi[qb0];
                a0 += ql.x*krlo.x + ql.y*krlo.y + ql.z*krlo.z + ql.w*krlo.w
                    + qh.x*krhi.x + qh.y*krhi.y + qh.z*krhi.z + qh.w*krhi.w;
                ql = *(const f4*)&qlo[64 + qb0];   qh = *(const f4*)&qhi[64 + qb0];
                a1 += ql.x*krlo.x + ql.y*krlo.y + ql.z*krlo.z + ql.w*krlo.w
                    + qh.x*krhi.x + qh.y*krhi.y + qh.z*krhi.z + qh.w*krhi.w;
                ql = *(const f4*)&qlo[128 + qb0];  qh = *(const f4*)&qhi[128 + qb0];
                a2 += ql.x*krlo.x + ql.y*krlo.y + ql.z*krlo.z + ql.w*krlo.w
                    + qh.x*krhi.x + qh.y*krhi.y + qh.z*krhi.z + qh.w*krhi.w;
                ql = *(const f4*)&qlo[192 + qb0];  qh = *(const f4*)&qhi[192 + qb0];
                a3 += ql.x*krlo.x + ql.y*krlo.y + ql.z*krlo.z + ql.w*krlo.w
                    + qh.x*krhi.x + qh.y*krhi.y + qh.z*krhi.z + qh.w*krhi.w;
            }
            a0 += __shfl_xor(a0, 1); a0 += __shfl_xor(a0, 2);
            a1 += __shfl_xor(a1, 1); a1 += __shfl_xor(a1, 2);
            a2 += __shfl_xor(a2, 1); a2 += __shfl_xor(a2, 2);
            a3 += __shfl_xor(a3, 1); a3 += __shfl_xor(a3, 2);
            if (j4 == 0 && tt4 < cn) {
                f4 sv; sv.x = a0; sv.y = a1; sv.z = a2; sv.w = a3;
                *(f4*)&sc[tt4 * 4] = sv;
            }
        }
        // table rows for next chunk (L2-hot; spans softmax+PV+stage)
        if (c + 1 < nc) LOADT(c + 1);
        __syncthreads();

        // ---- block softmax over the chunk ----
        const float sv = (tt4 < cn) ? sc[tt4 * 4 + j4] : -INFINITY;
        float pmax = sv;
        pmax = fmaxf(pmax, __shfl_xor(pmax, 4));
        pmax = fmaxf(pmax, __shfl_xor(pmax, 8));
        pmax = fmaxf(pmax, __shfl_xor(pmax, 16));
        pmax = fmaxf(pmax, __shfl_xor(pmax, 32));
        if ((tid & 63) < 4) redM[w][tid & 3] = pmax;
        __syncthreads();

        float Mn0 = Mr0, Mn1 = Mr1, Mn2 = Mr2, Mn3 = Mr3;
#pragma unroll
        for (int i = 0; i < 8; ++i) {
            Mn0 = fmaxf(Mn0, redM[i][0]); Mn1 = fmaxf(Mn1, redM[i][1]);
            Mn2 = fmaxf(Mn2, redM[i][2]); Mn3 = fmaxf(Mn3, redM[i][3]);
        }
        const float Mg = (j4 == 0) ? Mn0 : (j4 == 1) ? Mn1 : (j4 == 2) ? Mn2 : Mn3;
        float lsum = 0.f;
        if (tt4 < cn) {
            float p = __expf(sv - Mg);
            sc[tt4 * 4 + j4] = p;
            lsum = p;
        }
        lsum += __shfl_xor(lsum, 4);
        lsum += __shfl_xor(lsum, 8);
        lsum += __shfl_xor(lsum, 16);
        lsum += __shfl_xor(lsum, 32);
        if ((tid & 63) < 4) redL[w][tid & 3] = lsum;
        __syncthreads();

        {
            float Lc0 = 0.f, Lc1 = 0.f, Lc2 = 0.f, Lc3 = 0.f;
#pragma unroll
            for (int i = 0; i < 8; ++i) {
                Lc0 += redL[i][0]; Lc1 += redL[i][1];
                Lc2 += redL[i][2]; Lc3 += redL[i][3];
            }
            const float c0 = __expf(Mr0 - Mn0);   // first chunk: exp(-inf)=0
            const float c1 = __expf(Mr1 - Mn1);
            const float c2 = __expf(Mr2 - Mn2);
            const float c3 = __expf(Mr3 - Mn3);
            Lr0 = Lr0 * c0 + Lc0; o[0] *= c0; Mr0 = Mn0;
            Lr1 = Lr1 * c1 + Lc1; o[1] *= c1; Mr1 = Mn1;
            Lr2 = Lr2 * c2 + Lc2; o[2] *= c2; Mr2 = Mn2;
            Lr3 = Lr3 * c3 + Lc3; o[3] *= c3; Mr3 = Mn3;
        }

        // ---- PV from LDS (token per half-wave, p broadcast) ----
#pragma unroll
        for (int it = 0; it < 8; ++it) {
            int tt = hw + 16 * it;
            if (tt < cn) {
                f4 p4 = *(const f4*)&sc[tt * 4];
                f4 vv = *(const f4*)&Vt[tt * RS + 4 * il];
                o[0] += p4.x * vv; o[1] += p4.y * vv;
                o[2] += p4.z * vv; o[3] += p4.w * vv;
            }
        }
        __syncthreads();                 // PV done reading Vt/sc
        if (c + 1 < nc) WRITE(c + 1);    // vmcnt drains the prefetch here
        __syncthreads();                 // LDS ready for next dot
    }

    // ---- final combine across 16 half-waves ----
#pragma unroll
    for (int g = 0; g < 4; ++g) {
        o[g].x += __shfl_xor(o[g].x, 32);
        o[g].y += __shfl_xor(o[g].y, 32);
        o[g].z += __shfl_xor(o[g].z, 32);
        o[g].w += __shfl_xor(o[g].w, 32);
    }
    float* lod = Kt;   // alias: [8 waves][4 heads][HD], chunk loop is done
    if ((tid & 32) == 0) {
#pragma unroll
        for (int g = 0; g < 4; ++g)
            *(f4*)&lod[(w * 4 + g) * HD + 4 * il] = o[g];
    }
    __syncthreads();
    {
        const int d = tid & 127;
        const int g = tid >> 7;          // 512 threads = 4 heads x 128 dims
        float O = 0.f;
#pragma unroll
        for (int i = 0; i < 8; ++i) O += lod[(i * 4 + g) * HD + d];
        const float Lsel = (g == 0) ? Lr0 : (g == 1) ? Lr1 : (g == 2) ? Lr2 : Lr3;
        out[((size_t)b * NQH + h * GQA + g) * HD + d] = O / Lsel;
    }
}

extern "C" void kernel_launch(void* const* d_in, const int* in_sizes, int n_in,
                              void* d_out, int out_size, void* d_ws, size_t ws_size,
                              hipStream_t stream) {
    const float* q  = (const float*)d_in[0];
    const float* k  = (const float*)d_in[1];
    const float* v  = (const float*)d_in[2];
    const float* kc = (const float*)d_in[3];
    const float* vc = (const float*)d_in[4];
    const int*   bt = (const int*)d_in[5];
    int B  = in_sizes[0] / (NQH * HD);
    int nb = in_sizes[5] / B;
    int T  = nb * PBLK;

    float* out = (float*)d_out;
    float* tab = (float*)d_ws;
    size_t tabBytes = (size_t)(T + 1) * 128 * sizeof(float);
    int useTable = (ws_size >= tabBytes) ? 1 : 0;

    if (useTable) {
        int tot = (T + 1) * 64;
        rope_table_kernel<<<(tot + 255) / 256, 256, 0, stream>>>(tab, T);
    }
    paged_attn_kernel<<<B * NKVH, 512, 0, stream>>>(
        q, k, v, kc, vc, bt, tab, out, T, nb, useTable);
}

// Round 9
// 109.366 us; speedup vs baseline: 5.3207x; 5.3207x over previous
//
#include <hip/hip_runtime.h>
#include <math.h>

#define HD    128
#define NQH   32
#define NKVH  8
#define GQA   4
#define PBLK  16      // paged cache block size
#define MAXNB 512     // max block-table entries cached in LDS

#define L2_10000 13.287712379549449f   // log2(10000)

typedef float f4 __attribute__((ext_vector_type(4)));
typedef float f2 __attribute__((ext_vector_type(2)));

// token base pointer (K or V) for token t; t == T means "current" k/v
__device__ __forceinline__ const float* tok_base(
    const float* __restrict__ cache, const float* __restrict__ cur,
    const int* __restrict__ btrow, int t, int T, int b, int h)
{
    if (t == T) return cur + ((size_t)b * NKVH + h) * HD;
    int blk = btrow[t >> 4];
    return cache + (((size_t)blk * PBLK + (t & (PBLK - 1))) * NKVH + h) * HD;
}

// Round-2 proven streaming structure; the one change: NO sincosf in the inner
// loop. Rounds 2-7 all silently ran the useTable=0 fallback (d_ws too small
// for the rope table) => 2+ library sincosf per token per lane dominated and
// pinned every variant at ~170us (VALU-bound; L3-warm replays equally slow).
// Fix: per-lane complex-phase recurrence — cos/sin(t*inv_f) advanced by a
// fixed rotation (8 FMA/token). 6 sincosf total per lane (prologue only).
// No d_ws usage at all.
__global__ __launch_bounds__(1024) void paged_attn_kernel(
    const float* __restrict__ q,
    const float* __restrict__ kcur,
    const float* __restrict__ vcur,
    const float* __restrict__ kc,
    const float* __restrict__ vc,
    const int* __restrict__ bt,
    float* __restrict__ out,
    int T, int nb)
{
    const int b   = blockIdx.x >> 3;
    const int h   = blockIdx.x & 7;
    const int tid = threadIdx.x;
    const int hw  = tid >> 5;        // half-wave id 0..31
    const int il  = tid & 31;        // lane within half-wave
    const int d0v = il << 2;         // V/output dims [d0v, d0v+4)
    const int dk  = il << 1;         // K dims: {dk,dk+1} and {64+dk, 64+dk+1}

    // cache block table row in LDS
    __shared__ int sbt[MAXNB];
    const int* btrow = bt + (size_t)b * nb;
    if (nb <= MAXNB) {
        for (int i = tid; i < nb; i += 1024) sbt[i] = btrow[i];
        __syncthreads();
        btrow = sbt;
    }

    // this lane's two rope frequencies
    const float invf0 = exp2f(-(float)(dk)     * (L2_10000 / 64.0f));
    const float invf1 = exp2f(-(float)(dk + 1) * (L2_10000 / 64.0f));
    const float scale = 0.08838834764831845f;  // 128^-0.5

    // --- rope current q (4 GQA heads) at position T, scale folded in ---
    f4 qr[4];
    {
        float cT0, sT0, cT1, sT1;
        sincosf((float)T * invf0, &sT0, &cT0);
        sincosf((float)T * invf1, &sT1, &cT1);
        const float* qb = q + ((size_t)b * NQH + h * GQA) * HD;
#pragma unroll
        for (int g = 0; g < 4; ++g) {
            f2 xlo = *(const f2*)(qb + (size_t)g * HD + dk);
            f2 xhi = *(const f2*)(qb + (size_t)g * HD + 64 + dk);
            qr[g].x = (xlo.x * cT0 - xhi.x * sT0) * scale;
            qr[g].y = (xlo.y * cT1 - xhi.y * sT1) * scale;
            qr[g].z = (xhi.x * cT0 + xlo.x * sT0) * scale;
            qr[g].w = (xhi.y * cT1 + xlo.y * sT1) * scale;
        }
    }

    // --- rope phase recurrence for the K stream ---
    // cs(t) for t = hw, then advance by fixed rotation of angle 32*invf.
    float c0, s0, c1, s1, C0, S0, C1, S1;
    sincosf((float)hw * invf0, &s0, &c0);
    sincosf((float)hw * invf1, &s1, &c1);
    sincosf(32.0f * invf0, &S0, &C0);
    sincosf(32.0f * invf1, &S1, &C1);

    float m[4] = {-INFINITY, -INFINITY, -INFINITY, -INFINITY};
    float l[4] = {0.f, 0.f, 0.f, 0.f};
    f4 o[4] = {};

    // --- main loop: half-wave takes tokens t = hw, hw+32, ... (incl. t==T) ---
    int t = hw;
    f2 klo = {}, khi = {};
    f4 vv = {};
    if (t <= T) {
        const float* kb = tok_base(kc, kcur, btrow, t, T, b, h);
        const float* vb = tok_base(vc, vcur, btrow, t, T, b, h);
        klo = *(const f2*)(kb + dk);
        khi = *(const f2*)(kb + 64 + dk);
        vv  = *(const f4*)(vb + d0v);
    }
    for (; t <= T; t += 32) {
        // prefetch next token
        const int tn = t + 32;
        f2 klon = {}, khin = {};
        f4 vn = {};
        if (tn <= T) {
            const float* kb = tok_base(kc, kcur, btrow, tn, T, b, h);
            const float* vb = tok_base(vc, vcur, btrow, tn, T, b, h);
            klon = *(const f2*)(kb + dk);
            khin = *(const f2*)(kb + 64 + dk);
            vn   = *(const f4*)(vb + d0v);
        }

        // rope k with current phase (c0,s0,c1,s1)
        f4 kr;
        kr.x = klo.x * c0 - khi.x * s0;
        kr.y = klo.y * c1 - khi.y * s1;
        kr.z = khi.x * c0 + klo.x * s0;
        kr.w = khi.y * c1 + klo.y * s1;

        // advance phase by 32 positions (complex multiply, 8 FMA)
        {
            float nc0 = c0 * C0 - s0 * S0, ns0 = s0 * C0 + c0 * S0;
            float nc1 = c1 * C1 - s1 * S1, ns1 = s1 * C1 + c1 * S1;
            c0 = nc0; s0 = ns0; c1 = nc1; s1 = ns1;
        }

        float sc0 = qr[0].x * kr.x + qr[0].y * kr.y + qr[0].z * kr.z + qr[0].w * kr.w;
        float sc1 = qr[1].x * kr.x + qr[1].y * kr.y + qr[1].z * kr.z + qr[1].w * kr.w;
        float sc2 = qr[2].x * kr.x + qr[2].y * kr.y + qr[2].z * kr.z + qr[2].w * kr.w;
        float sc3 = qr[3].x * kr.x + qr[3].y * kr.y + qr[3].z * kr.z + qr[3].w * kr.w;
#pragma unroll
        for (int msk = 16; msk >= 1; msk >>= 1) {
            sc0 += __shfl_xor(sc0, msk);
            sc1 += __shfl_xor(sc1, msk);
            sc2 += __shfl_xor(sc2, msk);
            sc3 += __shfl_xor(sc3, msk);
        }
        float sarr[4] = {sc0, sc1, sc2, sc3};
#pragma unroll
        for (int g = 0; g < 4; ++g) {
            float sc = sarr[g];
            if (sc > m[g]) {                     // lazy rescale: rare (~log T times)
                float corr = __expf(m[g] - sc);
                l[g] *= corr;
                o[g] *= corr;
                m[g] = sc;
            }
            float p = __expf(sc - m[g]);
            l[g] += p;
            o[g] += p * vv;
        }
        klo = klon; khi = khin; vv = vn;
    }

    // --- combine the two half-waves of each wave (lanes l <-> l^32 same dims) ---
#pragma unroll
    for (int g = 0; g < 4; ++g) {
        float mo = __shfl_xor(m[g], 32);
        float M  = fmaxf(m[g], mo);
        float w  = (m[g] > -INFINITY) ? __expf(m[g] - M) : 0.f;
        float lw = l[g] * w;
        float Lc = lw + __shfl_xor(lw, 32);
        f4 ow = o[g] * w;
        f4 Oc;
        Oc.x = ow.x + __shfl_xor(ow.x, 32);
        Oc.y = ow.y + __shfl_xor(ow.y, 32);
        Oc.z = ow.z + __shfl_xor(ow.z, 32);
        Oc.w = ow.w + __shfl_xor(ow.w, 32);
        m[g] = M; l[g] = Lc; o[g] = Oc;
    }

    // --- cross-wave flash combine via LDS ---
    __shared__ float lm[16][4];
    __shared__ float ll[16][4];
    __shared__ float lodata[16][4][HD];
    const int w = tid >> 6;
    if ((tid & 32) == 0) {
        if (il == 0) {
#pragma unroll
            for (int g = 0; g < 4; ++g) { lm[w][g] = m[g]; ll[w][g] = l[g]; }
        }
#pragma unroll
        for (int g = 0; g < 4; ++g)
            *(f4*)(&lodata[w][g][d0v]) = o[g];
    }
    __syncthreads();

    if (tid < 512) {
        int g = tid >> 7;
        int d = tid & 127;
        float M = -INFINITY;
#pragma unroll
        for (int i = 0; i < 16; ++i) M = fmaxf(M, lm[i][g]);
        float L = 0.f, O = 0.f;
#pragma unroll
        for (int i = 0; i < 16; ++i) {
            float wgt = __expf(lm[i][g] - M);
            L += wgt * ll[i][g];
            O += wgt * lodata[i][g][d];
        }
        out[(size_t)b * (NQH * HD) + (size_t)(h * GQA + g) * HD + d] = O / L;
    }
}

extern "C" void kernel_launch(void* const* d_in, const int* in_sizes, int n_in,
                              void* d_out, int out_size, void* d_ws, size_t ws_size,
                              hipStream_t stream) {
    const float* q  = (const float*)d_in[0];
    const float* k  = (const float*)d_in[1];
    const float* v  = (const float*)d_in[2];
    const float* kc = (const float*)d_in[3];
    const float* vc = (const float*)d_in[4];
    const int*   bt = (const int*)d_in[5];
    int B  = in_sizes[0] / (NQH * HD);
    int nb = in_sizes[5] / B;
    int T  = nb * PBLK;

    float* out = (float*)d_out;
    paged_attn_kernel<<<B * NKVH, 1024, 0, stream>>>(q, k, v, kc, vc, bt, out, T, nb);
}